// Round 2
// baseline (189.433 us; speedup 1.0000x reference)
//
#include <hip/hip_runtime.h>
#include <hip/hip_bf16.h>

using short8 = __attribute__((ext_vector_type(8))) short;
using f32x4  = __attribute__((ext_vector_type(4))) float;

#define BM 128
#define BN 128
#define BK 64

__device__ inline void gload_lds16(const void* g, void* lds) {
    __builtin_amdgcn_global_load_lds(
        (const __attribute__((address_space(1))) void*)g,
        (__attribute__((address_space(3))) void*)lds, 16, 0, 0);
}

// Kernel 0: suffix-sum table ST[q][j] = sum_{k>=q} E[j][k]  (transposed for coalesced reads)
__global__ void suffix_kernel(const float* __restrict__ E, float* __restrict__ ST, int m) {
    int j = threadIdx.x;
    if (j >= m) return;
    float acc = 0.f;
    for (int k = m - 1; k >= 0; --k) {
        acc += E[(size_t)j * m + k];
        ST[(size_t)k * m + j] = acc;
    }
}

// Kernel 1: per-row prep — time-interp, normalize, /tau, bf16 cast, exact f32 diag g, acc init.
// One wave per row; assumes m == 256.
__global__ __launch_bounds__(256) void prep_kernel(
    const float* __restrict__ z, const float* __restrict__ t,
    const float* __restrict__ e, const float* __restrict__ log_tau,
    const float* __restrict__ E, const float* __restrict__ L,
    const float* __restrict__ ST,
    __hip_bfloat16* __restrict__ hz, __hip_bfloat16* __restrict__ hy,
    float* __restrict__ g, float* __restrict__ acc, int B, int m)
{
    int row  = blockIdx.x * 4 + (threadIdx.x >> 6);
    int lane = threadIdx.x & 63;
    if (row >= B) return;

    float tv = t[row], ev = e[row];

    // searchsorted (side='left'): first idx with L[idx] >= t
    int lo = 0, hi = m;
    while (lo < hi) { int mid = (lo + hi) >> 1; if (L[mid] < tv) lo = mid + 1; else hi = mid; }
    int idx = lo;
    if (idx == 0) idx = 1;
    if (idx == m) idx = m - 1;

    float Llo = L[idx - 1], Lhi = L[idx];
    float w    = (tv - Llo) / (Lhi - Llo);
    float invd = 1.0f / (float)(m - idx);
    float tau  = sqrtf(expf(log_tau[0]));
    float invtau = 1.0f / tau;

    float yv[4], zv[4];
    float ssy = 0.f, ssz = 0.f;
    #pragma unroll
    for (int p = 0; p < 4; ++p) {
        int j = lane + p * 64;
        float Elo = E[(size_t)(idx - 1) * m + j];
        float Ehi = E[(size_t)idx * m + j];
        float yint = Elo + (Ehi - Elo) * w;
        float ycen = ST[(size_t)idx * m + j] * invd;
        float y = yint * ev + ycen * (1.f - ev);
        yv[p] = y; ssy += y * y;
        float zz = z[(size_t)row * m + j];
        zv[p] = zz; ssz += zz * zz;
    }
    #pragma unroll
    for (int off = 1; off < 64; off <<= 1) {
        ssy += __shfl_xor(ssy, off);
        ssz += __shfl_xor(ssz, off);
    }
    float sy = invtau / fmaxf(sqrtf(ssy), 1e-12f);
    float sz = invtau / fmaxf(sqrtf(ssz), 1e-12f);

    float gp = 0.f;
    #pragma unroll
    for (int p = 0; p < 4; ++p) {
        int j = lane + p * 64;
        float hyv = yv[p] * sy, hzv = zv[p] * sz;
        gp += hyv * hzv;
        hy[(size_t)row * m + j] = __float2bfloat16(hyv);
        hz[(size_t)row * m + j] = __float2bfloat16(hzv);
    }
    #pragma unroll
    for (int off = 1; off < 64; off <<= 1) gp += __shfl_xor(gp, off);
    if (lane == 0) { g[row] = gp; acc[row] = 0.f; }
}

// Kernel 2: fused sim = hz @ hy^T tile + exp + row partial sums (atomic accumulate).
// 128x128 tile, 4 waves (2x2), each wave 64x64, K iterated in BK=64 steps.
// LDS layout [row][64] bf16 with XOR chunk swizzle (rule 21): linear global_load_lds dest,
// inverse-swizzled global source, swizzled ds_read_b128.
__global__ __launch_bounds__(256, 2) void gemm_lse_kernel(
    const __hip_bfloat16* __restrict__ hz, const __hip_bfloat16* __restrict__ hy,
    float* __restrict__ row_acc, int B, int K)
{
    __shared__ __hip_bfloat16 As[BM * BK];
    __shared__ __hip_bfloat16 Bs[BN * BK];

    const int tid  = threadIdx.x;
    const int wv   = tid >> 6;
    const int lane = tid & 63;
    const int wr   = wv >> 1;   // wave row 0..1
    const int wc   = wv & 1;    // wave col 0..1
    const int row0 = blockIdx.y * BM;
    const int col0 = blockIdx.x * BN;

    f32x4 acc[4][4];
    #pragma unroll
    for (int i = 0; i < 4; ++i)
        #pragma unroll
        for (int j = 0; j < 4; ++j)
            acc[i][j] = (f32x4){0.f, 0.f, 0.f, 0.f};

    const int l8 = lane >> 3;  // row within 8-row wave chunk
    const int c8 = lane & 7;   // 16B chunk id within 128B row

    const int nkb = K / BK;
    for (int kb = 0; kb < nkb; ++kb) {
        #pragma unroll
        for (int p = 0; p < 4; ++p) {
            int r  = p * 32 + wv * 8 + l8;      // tile row 0..127
            int cg = c8 ^ (r & 7);              // inverse-swizzled source chunk
            gload_lds16(hz + (size_t)(row0 + r) * K + kb * BK + cg * 8,
                        (void*)&As[(p * 32 + wv * 8) * BK]);
            gload_lds16(hy + (size_t)(col0 + r) * K + kb * BK + cg * 8,
                        (void*)&Bs[(p * 32 + wv * 8) * BK]);
        }
        __syncthreads();

        const int lm = lane & 15, lk = lane >> 4;
        #pragma unroll
        for (int kk = 0; kk < 2; ++kk) {
            short8 a[4], b[4];
            #pragma unroll
            for (int mi = 0; mi < 4; ++mi) {
                int rt = wr * 64 + mi * 16 + lm;
                int cs = (kk * 4 + lk) ^ (rt & 7);
                a[mi] = *(const short8*)&As[rt * BK + cs * 8];
            }
            #pragma unroll
            for (int ni = 0; ni < 4; ++ni) {
                int rt = wc * 64 + ni * 16 + lm;
                int cs = (kk * 4 + lk) ^ (rt & 7);
                b[ni] = *(const short8*)&Bs[rt * BK + cs * 8];
            }
            #pragma unroll
            for (int mi = 0; mi < 4; ++mi)
                #pragma unroll
                for (int ni = 0; ni < 4; ++ni)
                    acc[mi][ni] = __builtin_amdgcn_mfma_f32_16x16x32_bf16(
                        a[mi], b[ni], acc[mi][ni], 0, 0, 0);
        }
        __syncthreads();
    }

    // Epilogue: exp + row sums. C/D layout: col = lane&15, row = (lane>>4)*4 + reg.
    const int lm = lane & 15, lg = lane >> 4;
    #pragma unroll
    for (int mi = 0; mi < 4; ++mi) {
        float rs[4] = {0.f, 0.f, 0.f, 0.f};
        #pragma unroll
        for (int ni = 0; ni < 4; ++ni) {
            #pragma unroll
            for (int r = 0; r < 4; ++r) rs[r] += __expf(acc[mi][ni][r]);
        }
        #pragma unroll
        for (int r = 0; r < 4; ++r) {
            float s = rs[r];
            s += __shfl_xor(s, 1);
            s += __shfl_xor(s, 2);
            s += __shfl_xor(s, 4);
            s += __shfl_xor(s, 8);
            if (lm == 0)
                unsafeAtomicAdd(&row_acc[row0 + wr * 64 + mi * 16 + lg * 4 + r], s);
        }
    }
}

// Kernel 3: out = clip(log(acc) - g - log(B), -5, 15)
__global__ void finalize_kernel(const float* __restrict__ acc, const float* __restrict__ g,
                                float* __restrict__ out, int B) {
    int i = blockIdx.x * 256 + threadIdx.x;
    if (i < B) {
        float v = logf(acc[i]) - g[i] - logf((float)B);
        out[i] = fminf(fmaxf(v, -5.f), 15.f);
    }
}

extern "C" void kernel_launch(void* const* d_in, const int* in_sizes, int n_in,
                              void* d_out, int out_size, void* d_ws, size_t ws_size,
                              hipStream_t stream) {
    const float* z       = (const float*)d_in[0];
    const float* t       = (const float*)d_in[1];
    const float* e       = (const float*)d_in[2];
    const float* log_tau = (const float*)d_in[3];
    const float* E       = (const float*)d_in[4];
    const float* L       = (const float*)d_in[5];
    float* out = (float*)d_out;

    const int B = in_sizes[1];   // 8192
    const int m = in_sizes[5];   // 256

    // workspace layout
    char* w = (char*)d_ws;
    __hip_bfloat16* hz = (__hip_bfloat16*)w;                 // B*m bf16
    __hip_bfloat16* hy = hz + (size_t)B * m;                 // B*m bf16
    float* ST  = (float*)(hy + (size_t)B * m);               // m*m f32
    float* g   = ST + (size_t)m * m;                         // B f32
    float* acc = g + B;                                      // B f32

    suffix_kernel<<<1, m, 0, stream>>>(E, ST, m);
    prep_kernel<<<B / 4, 256, 0, stream>>>(z, t, e, log_tau, E, L, ST, hz, hy, g, acc, B, m);
    dim3 grid2(B / BN, B / BM);
    gemm_lse_kernel<<<grid2, 256, 0, stream>>>(hz, hy, acc, B, m);
    finalize_kernel<<<(B + 255) / 256, 256, 0, stream>>>(acc, g, out, B);
}

// Round 3
// 141.843 us; speedup vs baseline: 1.3355x; 1.3355x over previous
//
#include <hip/hip_runtime.h>
#include <hip/hip_bf16.h>

using short8 = __attribute__((ext_vector_type(8))) short;
using f32x4  = __attribute__((ext_vector_type(4))) float;

#define BM 128
#define BN 128
#define BK 64

__device__ inline void gload_lds16(const void* g, void* lds) {
    __builtin_amdgcn_global_load_lds(
        (const __attribute__((address_space(1))) void*)g,
        (__attribute__((address_space(3))) void*)lds, 16, 0, 0);
}

// Kernel 0: suffix-sum table ST[k][j] = sum_{q>=k} E[j][q].
// One block per row j; wave-level suffix scan + cross-wave LDS combine.
__global__ __launch_bounds__(256) void suffix_kernel(const float* __restrict__ E,
                                                     float* __restrict__ ST, int m) {
    int j = blockIdx.x;
    int k = threadIdx.x;
    int lane = k & 63, w = k >> 6;
    __shared__ float wtot[4];
    float v = (k < m) ? E[(size_t)j * m + k] : 0.f;
    #pragma unroll
    for (int off = 1; off < 64; off <<= 1) {
        float o = __shfl_down(v, off);
        if (lane + off < 64) v += o;
    }
    if (lane == 0) wtot[w] = v;   // wave total (suffix at lane 0)
    __syncthreads();
    float add = 0.f;
    #pragma unroll
    for (int w2 = 0; w2 < 4; ++w2)
        if (w2 > w) add += wtot[w2];
    v += add;
    if (k < m) ST[(size_t)k * m + j] = v;
}

// Kernel 1: per-row prep — time-interp, normalize, /tau, bf16 cast, exact f32 diag g, acc init.
// One wave per row; lane owns 4 consecutive columns (vectorized float4). Assumes m == 256.
__global__ __launch_bounds__(256) void prep_kernel(
    const float* __restrict__ z, const float* __restrict__ t,
    const float* __restrict__ e, const float* __restrict__ log_tau,
    const float* __restrict__ E, const float* __restrict__ L,
    const float* __restrict__ ST,
    __hip_bfloat16* __restrict__ hz, __hip_bfloat16* __restrict__ hy,
    float* __restrict__ g, float* __restrict__ acc, int B, int m)
{
    int row  = blockIdx.x * 4 + (threadIdx.x >> 6);
    int lane = threadIdx.x & 63;
    if (row >= B) return;

    float tv = t[row], ev = e[row];

    // searchsorted (side='left'): first idx with L[idx] >= t
    int lo = 0, hi = m;
    while (lo < hi) { int mid = (lo + hi) >> 1; if (L[mid] < tv) lo = mid + 1; else hi = mid; }
    int idx = lo;
    if (idx == 0) idx = 1;
    if (idx == m) idx = m - 1;

    float Llo = L[idx - 1], Lhi = L[idx];
    float w    = (tv - Llo) / (Lhi - Llo);
    float invd = 1.0f / (float)(m - idx);
    float tau  = sqrtf(expf(log_tau[0]));
    float invtau = 1.0f / tau;

    int j0 = lane * 4;
    f32x4 zz = *(const f32x4*)&z[(size_t)row * m + j0];
    f32x4 El = *(const f32x4*)&E[(size_t)(idx - 1) * m + j0];
    f32x4 Eh = *(const f32x4*)&E[(size_t)idx * m + j0];
    f32x4 Sc = *(const f32x4*)&ST[(size_t)idx * m + j0];

    float yv[4];
    float ssy = 0.f, ssz = 0.f;
    #pragma unroll
    for (int p = 0; p < 4; ++p) {
        float yint = El[p] + (Eh[p] - El[p]) * w;
        float ycen = Sc[p] * invd;
        float y = yint * ev + ycen * (1.f - ev);
        yv[p] = y; ssy += y * y;
        ssz += zz[p] * zz[p];
    }
    #pragma unroll
    for (int off = 1; off < 64; off <<= 1) {
        ssy += __shfl_xor(ssy, off);
        ssz += __shfl_xor(ssz, off);
    }
    float sy = invtau / fmaxf(sqrtf(ssy), 1e-12f);
    float sz = invtau / fmaxf(sqrtf(ssz), 1e-12f);

    float gp = 0.f;
    ushort uy[4], uz[4];
    #pragma unroll
    for (int p = 0; p < 4; ++p) {
        float hyv = yv[p] * sy, hzv = zz[p] * sz;
        gp += hyv * hzv;
        __hip_bfloat16 hb = __float2bfloat16(hyv);
        __hip_bfloat16 zb = __float2bfloat16(hzv);
        uy[p] = *reinterpret_cast<unsigned short*>(&hb);
        uz[p] = *reinterpret_cast<unsigned short*>(&zb);
    }
    *(ushort4*)&hy[(size_t)row * m + j0] = make_ushort4(uy[0], uy[1], uy[2], uy[3]);
    *(ushort4*)&hz[(size_t)row * m + j0] = make_ushort4(uz[0], uz[1], uz[2], uz[3]);
    #pragma unroll
    for (int off = 1; off < 64; off <<= 1) gp += __shfl_xor(gp, off);
    if (lane == 0) { g[row] = gp; acc[row] = 0.f; }
}

// Kernel 2: fused sim = hz @ hy^T tile + exp + row partial sums (atomic accumulate).
// 128x128 tile, 4 waves (2x2), double-buffered LDS, 2-phase prefetch (counted vmcnt,
// raw s_barrier — never drain vmcnt to 0 mid-loop), XCD-aware block swizzle.
__global__ __launch_bounds__(256, 2) void gemm_lse_kernel(
    const __hip_bfloat16* __restrict__ hz, const __hip_bfloat16* __restrict__ hy,
    float* __restrict__ row_acc, int B, int K)
{
    __shared__ __hip_bfloat16 As[2][BM * BK];
    __shared__ __hip_bfloat16 Bs[2][BN * BK];

    const int tid  = threadIdx.x;
    const int wv   = tid >> 6;
    const int lane = tid & 63;
    const int wr   = wv >> 1;   // wave row 0..1
    const int wc   = wv & 1;    // wave col 0..1

    // XCD-aware swizzle: XCD k owns an 8-row stripe of tiles (by in [8k,8k+8)),
    // ordered by-fast / bx-slow so each B-panel gets 8 back-to-back reuses and the
    // stripe's 8 A-panels (512 KB) stay L2-resident. Bijective (nwg % 8 == 0).
    int bx = blockIdx.x, by = blockIdx.y;
    {
        int nx = gridDim.x, ny = gridDim.y;
        int nwg = nx * ny;
        if ((nwg & 7) == 0 && ny >= 8) {
            int orig = by * nx + bx;
            int xcd = orig & 7;
            int pos = orig >> 3;
            by = (xcd << 3) | (pos & 7);
            bx = pos >> 3;
        }
    }
    const int row0 = by * BM;
    const int col0 = bx * BN;

    f32x4 acc[4][4];
    #pragma unroll
    for (int i = 0; i < 4; ++i)
        #pragma unroll
        for (int j = 0; j < 4; ++j)
            acc[i][j] = (f32x4){0.f, 0.f, 0.f, 0.f};

    const int l8 = lane >> 3;  // row within 8-row wave chunk
    const int c8 = lane & 7;   // 16B chunk id within 128B row

    const int nkb = K / BK;

    // STAGE(buf, kb): 8 gload_lds per thread; LDS dest linear, global source
    // inverse-swizzled (rule 21).
#define STAGE(buf, kb)                                                          \
    do {                                                                        \
        _Pragma("unroll")                                                       \
        for (int p = 0; p < 4; ++p) {                                           \
            int r  = p * 32 + wv * 8 + l8;                                      \
            int cg = c8 ^ (r & 7);                                              \
            gload_lds16(hz + (size_t)(row0 + r) * K + (kb) * BK + cg * 8,       \
                        (void*)&As[buf][(p * 32 + wv * 8) * BK]);               \
            gload_lds16(hy + (size_t)(col0 + r) * K + (kb) * BK + cg * 8,       \
                        (void*)&Bs[buf][(p * 32 + wv * 8) * BK]);               \
        }                                                                       \
    } while (0)

    STAGE(0, 0);

    for (int kb = 0; kb < nkb; ++kb) {
        const int cur = kb & 1;
        asm volatile("" ::: "memory");
        if (kb + 1 < nkb) {
            STAGE(cur ^ 1, kb + 1);
            asm volatile("s_waitcnt vmcnt(8)" ::: "memory");  // cur's 8 loads done
        } else {
            asm volatile("s_waitcnt vmcnt(0)" ::: "memory");
        }
        __builtin_amdgcn_s_barrier();   // all waves' cur stage complete

        const int lm = lane & 15, lk = lane >> 4;
        #pragma unroll
        for (int kk = 0; kk < 2; ++kk) {
            short8 a[4], b[4];
            #pragma unroll
            for (int mi = 0; mi < 4; ++mi) {
                int rt = wr * 64 + mi * 16 + lm;
                int cs = (kk * 4 + lk) ^ (rt & 7);
                a[mi] = *(const short8*)&As[cur][rt * BK + cs * 8];
            }
            #pragma unroll
            for (int ni = 0; ni < 4; ++ni) {
                int rt = wc * 64 + ni * 16 + lm;
                int cs = (kk * 4 + lk) ^ (rt & 7);
                b[ni] = *(const short8*)&Bs[cur][rt * BK + cs * 8];
            }
            #pragma unroll
            for (int mi = 0; mi < 4; ++mi)
                #pragma unroll
                for (int ni = 0; ni < 4; ++ni)
                    acc[mi][ni] = __builtin_amdgcn_mfma_f32_16x16x32_bf16(
                        a[mi], b[ni], acc[mi][ni], 0, 0, 0);
        }
        __builtin_amdgcn_s_barrier();   // all reads of buf[cur] done before overwrite
    }
#undef STAGE

    // Epilogue: exp + row sums. C/D layout: col = lane&15, row = (lane>>4)*4 + reg.
    const int lm = lane & 15, lg = lane >> 4;
    #pragma unroll
    for (int mi = 0; mi < 4; ++mi) {
        float rs[4] = {0.f, 0.f, 0.f, 0.f};
        #pragma unroll
        for (int ni = 0; ni < 4; ++ni) {
            #pragma unroll
            for (int r = 0; r < 4; ++r) rs[r] += __expf(acc[mi][ni][r]);
        }
        #pragma unroll
        for (int r = 0; r < 4; ++r) {
            float s = rs[r];
            s += __shfl_xor(s, 1);
            s += __shfl_xor(s, 2);
            s += __shfl_xor(s, 4);
            s += __shfl_xor(s, 8);
            if (lm == 0)
                unsafeAtomicAdd(&row_acc[row0 + wr * 64 + mi * 16 + lg * 4 + r], s);
        }
    }
}

// Kernel 3: out = clip(log(acc) - g - log(B), -5, 15)
__global__ void finalize_kernel(const float* __restrict__ acc, const float* __restrict__ g,
                                float* __restrict__ out, int B) {
    int i = blockIdx.x * 256 + threadIdx.x;
    if (i < B) {
        float v = logf(acc[i]) - g[i] - logf((float)B);
        out[i] = fminf(fmaxf(v, -5.f), 15.f);
    }
}

extern "C" void kernel_launch(void* const* d_in, const int* in_sizes, int n_in,
                              void* d_out, int out_size, void* d_ws, size_t ws_size,
                              hipStream_t stream) {
    const float* z       = (const float*)d_in[0];
    const float* t       = (const float*)d_in[1];
    const float* e       = (const float*)d_in[2];
    const float* log_tau = (const float*)d_in[3];
    const float* E       = (const float*)d_in[4];
    const float* L       = (const float*)d_in[5];
    float* out = (float*)d_out;

    const int B = in_sizes[1];   // 8192
    const int m = in_sizes[5];   // 256

    // workspace layout
    char* w = (char*)d_ws;
    __hip_bfloat16* hz = (__hip_bfloat16*)w;                 // B*m bf16
    __hip_bfloat16* hy = hz + (size_t)B * m;                 // B*m bf16
    float* ST  = (float*)(hy + (size_t)B * m);               // m*m f32
    float* g   = ST + (size_t)m * m;                         // B f32
    float* acc = g + B;                                      // B f32

    suffix_kernel<<<m, 256, 0, stream>>>(E, ST, m);
    prep_kernel<<<B / 4, 256, 0, stream>>>(z, t, e, log_tau, E, L, ST, hz, hy, g, acc, B, m);
    dim3 grid2(B / BN, B / BM);
    gemm_lse_kernel<<<grid2, 256, 0, stream>>>(hz, hy, acc, B, m);
    finalize_kernel<<<(B + 255) / 256, 256, 0, stream>>>(acc, g, out, B);
}

// Round 4
// 135.113 us; speedup vs baseline: 1.4020x; 1.0498x over previous
//
#include <hip/hip_runtime.h>
#include <hip/hip_bf16.h>

using short8 = __attribute__((ext_vector_type(8))) short;
using f32x4  = __attribute__((ext_vector_type(4))) float;

#define BM 256
#define BN 256
#define BK 64
#define NKT 4   // K = 256 = NKT * BK (fixed by problem)

__device__ inline void gload_lds16(const void* g, void* lds) {
    __builtin_amdgcn_global_load_lds(
        (const __attribute__((address_space(1))) void*)g,
        (__attribute__((address_space(3))) void*)lds, 16, 0, 0);
}

// Kernel 0: suffix-sum table ST[k][j] = sum_{q>=k} E[j][q].
__global__ __launch_bounds__(256) void suffix_kernel(const float* __restrict__ E,
                                                     float* __restrict__ ST, int m) {
    int j = blockIdx.x;
    int k = threadIdx.x;
    int lane = k & 63, w = k >> 6;
    __shared__ float wtot[4];
    float v = (k < m) ? E[(size_t)j * m + k] : 0.f;
    #pragma unroll
    for (int off = 1; off < 64; off <<= 1) {
        float o = __shfl_down(v, off);
        if (lane + off < 64) v += o;
    }
    if (lane == 0) wtot[w] = v;
    __syncthreads();
    float add = 0.f;
    #pragma unroll
    for (int w2 = 0; w2 < 4; ++w2)
        if (w2 > w) add += wtot[w2];
    v += add;
    if (k < m) ST[(size_t)k * m + j] = v;
}

// Kernel 1: per-row prep — time-interp, normalize, /tau, bf16 cast, exact f32 diag g, acc init.
__global__ __launch_bounds__(256) void prep_kernel(
    const float* __restrict__ z, const float* __restrict__ t,
    const float* __restrict__ e, const float* __restrict__ log_tau,
    const float* __restrict__ E, const float* __restrict__ L,
    const float* __restrict__ ST,
    __hip_bfloat16* __restrict__ hz, __hip_bfloat16* __restrict__ hy,
    float* __restrict__ g, float* __restrict__ acc, int B, int m)
{
    int row  = blockIdx.x * 4 + (threadIdx.x >> 6);
    int lane = threadIdx.x & 63;
    if (row >= B) return;

    float tv = t[row], ev = e[row];

    int lo = 0, hi = m;
    while (lo < hi) { int mid = (lo + hi) >> 1; if (L[mid] < tv) lo = mid + 1; else hi = mid; }
    int idx = lo;
    if (idx == 0) idx = 1;
    if (idx == m) idx = m - 1;

    float Llo = L[idx - 1], Lhi = L[idx];
    float w    = (tv - Llo) / (Lhi - Llo);
    float invd = 1.0f / (float)(m - idx);
    float tau  = sqrtf(expf(log_tau[0]));
    float invtau = 1.0f / tau;

    int j0 = lane * 4;
    f32x4 zz = *(const f32x4*)&z[(size_t)row * m + j0];
    f32x4 El = *(const f32x4*)&E[(size_t)(idx - 1) * m + j0];
    f32x4 Eh = *(const f32x4*)&E[(size_t)idx * m + j0];
    f32x4 Sc = *(const f32x4*)&ST[(size_t)idx * m + j0];

    float yv[4];
    float ssy = 0.f, ssz = 0.f;
    #pragma unroll
    for (int p = 0; p < 4; ++p) {
        float yint = El[p] + (Eh[p] - El[p]) * w;
        float ycen = Sc[p] * invd;
        float y = yint * ev + ycen * (1.f - ev);
        yv[p] = y; ssy += y * y;
        ssz += zz[p] * zz[p];
    }
    #pragma unroll
    for (int off = 1; off < 64; off <<= 1) {
        ssy += __shfl_xor(ssy, off);
        ssz += __shfl_xor(ssz, off);
    }
    float sy = invtau / fmaxf(sqrtf(ssy), 1e-12f);
    float sz = invtau / fmaxf(sqrtf(ssz), 1e-12f);

    float gp = 0.f;
    ushort uy[4], uz[4];
    #pragma unroll
    for (int p = 0; p < 4; ++p) {
        float hyv = yv[p] * sy, hzv = zz[p] * sz;
        gp += hyv * hzv;
        __hip_bfloat16 hb = __float2bfloat16(hyv);
        __hip_bfloat16 zb = __float2bfloat16(hzv);
        uy[p] = *reinterpret_cast<unsigned short*>(&hb);
        uz[p] = *reinterpret_cast<unsigned short*>(&zb);
    }
    *(ushort4*)&hy[(size_t)row * m + j0] = make_ushort4(uy[0], uy[1], uy[2], uy[3]);
    *(ushort4*)&hz[(size_t)row * m + j0] = make_ushort4(uz[0], uz[1], uz[2], uz[3]);
    #pragma unroll
    for (int off = 1; off < 64; off <<= 1) gp += __shfl_xor(gp, off);
    if (lane == 0) { g[row] = gp; acc[row] = 0.f; }
}

// Kernel 2: fused sim = hz @ hy^T + exp + row partial sums.
// 256x256 tile, 8 waves (2M x 4N, per-wave 128x64), BK=64, double-buffered 128KB LDS,
// 4-phase-per-K-tile schedule (m201-style): {ds_read subtile | stage prefetch} ->
// barrier -> setprio(1) + 16 MFMA -> setprio(0) -> barrier. One vmcnt(0) fence per K-tile.
__global__ __launch_bounds__(512, 2) void gemm_lse_kernel(
    const __hip_bfloat16* __restrict__ hz, const __hip_bfloat16* __restrict__ hy,
    float* __restrict__ row_acc, int Brows, int K)
{
    __shared__ __hip_bfloat16 As[2][BM * BK];
    __shared__ __hip_bfloat16 Bs[2][BN * BK];

    const int tid  = threadIdx.x;
    const int wid  = tid >> 6;   // 0..7
    const int lane = tid & 63;
    const int wm   = wid >> 2;   // 0..1  (M half)
    const int wn   = wid & 3;    // 0..3  (N quarter)

    // XCD-aware swizzle: XCD k owns a 4-row stripe of tiles; bijective for 32x32 grid.
    int bx = blockIdx.x, by = blockIdx.y;
    if (gridDim.x == 32 && gridDim.y == 32) {
        int orig = by * 32 + bx;
        int xcd = orig & 7, pos = orig >> 3;
        by = (xcd << 2) | (pos & 3);
        bx = pos >> 2;
    }
    const int row0 = by * BM, col0 = bx * BN;

    f32x4 acc[8][4];
    #pragma unroll
    for (int i = 0; i < 8; ++i)
        #pragma unroll
        for (int j = 0; j < 4; ++j)
            acc[i][j] = (f32x4){0.f, 0.f, 0.f, 0.f};

    // staging geometry: 512 threads cover 64 rows x 128B per load-set
    const int srow = tid >> 3;            // 0..63 (row within a 64-row set)
    const int c8   = tid & 7;             // 16B chunk within 128B row
    const int cg   = c8 ^ (srow & 7);     // inverse-swizzled global chunk (rule 21)
    const int lm   = lane & 15, lk = lane >> 4;

#define STAGE_A(buf, kt)                                                        \
    do {                                                                        \
        _Pragma("unroll")                                                       \
        for (int s = 0; s < 4; ++s)                                             \
            gload_lds16(hz + (size_t)(row0 + s * 64 + srow) * K + (kt) * BK + cg * 8, \
                        (void*)&As[buf][s * 4096 + wid * 512]);                 \
    } while (0)
#define STAGE_B(buf, kt)                                                        \
    do {                                                                        \
        _Pragma("unroll")                                                       \
        for (int s = 0; s < 4; ++s)                                             \
            gload_lds16(hy + (size_t)(col0 + s * 64 + srow) * K + (kt) * BK + cg * 8, \
                        (void*)&Bs[buf][s * 4096 + wid * 512]);                 \
    } while (0)

    // swizzled LDS fragment read: row rt, K-chunk q (0..7 within BK)
#define LDSA(buf, rt, q) (*(const short8*)&As[buf][(rt) * BK + ((q) ^ ((rt) & 7)) * 8])
#define LDSB(buf, rt, q) (*(const short8*)&Bs[buf][(rt) * BK + ((q) ^ ((rt) & 7)) * 8])

    // prologue: stage K-tile 0 into buf 0
    STAGE_A(0, 0);
    STAGE_B(0, 0);
    asm volatile("s_waitcnt vmcnt(0)" ::: "memory");
    __builtin_amdgcn_s_barrier();

    #pragma unroll
    for (int kt = 0; kt < NKT; ++kt) {
        const int cur = kt & 1, nxt = cur ^ 1;
        short8 a[4], b[4];

        // ---- phase 0: kk=0, M-half 0; prefetch next A ----
        #pragma unroll
        for (int mi = 0; mi < 4; ++mi)
            a[mi] = LDSA(cur, wm * 128 + mi * 16 + lm, lk);
        #pragma unroll
        for (int ni = 0; ni < 4; ++ni)
            b[ni] = LDSB(cur, wn * 64 + ni * 16 + lm, lk);
        if (kt + 1 < NKT) STAGE_A(nxt, kt + 1);
        __builtin_amdgcn_s_barrier();
        __builtin_amdgcn_s_setprio(1);
        #pragma unroll
        for (int mi = 0; mi < 4; ++mi)
            #pragma unroll
            for (int ni = 0; ni < 4; ++ni)
                acc[mi][ni] = __builtin_amdgcn_mfma_f32_16x16x32_bf16(a[mi], b[ni], acc[mi][ni], 0, 0, 0);
        __builtin_amdgcn_s_setprio(0);
        __builtin_amdgcn_s_barrier();

        // ---- phase 1: kk=0, M-half 1 (reuse b); prefetch next B ----
        #pragma unroll
        for (int mi = 0; mi < 4; ++mi)
            a[mi] = LDSA(cur, wm * 128 + 64 + mi * 16 + lm, lk);
        if (kt + 1 < NKT) STAGE_B(nxt, kt + 1);
        __builtin_amdgcn_s_barrier();
        __builtin_amdgcn_s_setprio(1);
        #pragma unroll
        for (int mi = 0; mi < 4; ++mi)
            #pragma unroll
            for (int ni = 0; ni < 4; ++ni)
                acc[4 + mi][ni] = __builtin_amdgcn_mfma_f32_16x16x32_bf16(a[mi], b[ni], acc[4 + mi][ni], 0, 0, 0);
        __builtin_amdgcn_s_setprio(0);
        __builtin_amdgcn_s_barrier();

        // ---- phase 2: kk=1, M-half 0 ----
        #pragma unroll
        for (int mi = 0; mi < 4; ++mi)
            a[mi] = LDSA(cur, wm * 128 + mi * 16 + lm, 4 + lk);
        #pragma unroll
        for (int ni = 0; ni < 4; ++ni)
            b[ni] = LDSB(cur, wn * 64 + ni * 16 + lm, 4 + lk);
        __builtin_amdgcn_s_barrier();
        __builtin_amdgcn_s_setprio(1);
        #pragma unroll
        for (int mi = 0; mi < 4; ++mi)
            #pragma unroll
            for (int ni = 0; ni < 4; ++ni)
                acc[mi][ni] = __builtin_amdgcn_mfma_f32_16x16x32_bf16(a[mi], b[ni], acc[mi][ni], 0, 0, 0);
        __builtin_amdgcn_s_setprio(0);
        __builtin_amdgcn_s_barrier();

        // ---- phase 3: kk=1, M-half 1 ----
        #pragma unroll
        for (int mi = 0; mi < 4; ++mi)
            a[mi] = LDSA(cur, wm * 128 + 64 + mi * 16 + lm, 4 + lk);
        __builtin_amdgcn_s_barrier();
        __builtin_amdgcn_s_setprio(1);
        #pragma unroll
        for (int mi = 0; mi < 4; ++mi)
            #pragma unroll
            for (int ni = 0; ni < 4; ++ni)
                acc[4 + mi][ni] = __builtin_amdgcn_mfma_f32_16x16x32_bf16(a[mi], b[ni], acc[4 + mi][ni], 0, 0, 0);
        __builtin_amdgcn_s_setprio(0);
        // K-tile fence: next-tile staging must be complete (per-wave drain + barrier)
        asm volatile("s_waitcnt vmcnt(0)" ::: "memory");
        __builtin_amdgcn_s_barrier();
    }
#undef STAGE_A
#undef STAGE_B
#undef LDSA
#undef LDSB

    // Epilogue: exp + row sums. C/D: col = lane&15, row = (lane>>4)*4 + reg.
    const int lg = lane >> 4;
    #pragma unroll
    for (int mi = 0; mi < 8; ++mi) {
        float rs[4] = {0.f, 0.f, 0.f, 0.f};
        #pragma unroll
        for (int ni = 0; ni < 4; ++ni) {
            #pragma unroll
            for (int r = 0; r < 4; ++r) rs[r] += __expf(acc[mi][ni][r]);
        }
        #pragma unroll
        for (int r = 0; r < 4; ++r) {
            float s = rs[r];
            s += __shfl_xor(s, 1);
            s += __shfl_xor(s, 2);
            s += __shfl_xor(s, 4);
            s += __shfl_xor(s, 8);
            if (lm == 0)
                unsafeAtomicAdd(&row_acc[row0 + wm * 128 + mi * 16 + lg * 4 + r], s);
        }
    }
}

// Kernel 3: out = clip(log(acc) - g - log(B), -5, 15)
__global__ void finalize_kernel(const float* __restrict__ acc, const float* __restrict__ g,
                                float* __restrict__ out, int B) {
    int i = blockIdx.x * 256 + threadIdx.x;
    if (i < B) {
        float v = logf(acc[i]) - g[i] - logf((float)B);
        out[i] = fminf(fmaxf(v, -5.f), 15.f);
    }
}

extern "C" void kernel_launch(void* const* d_in, const int* in_sizes, int n_in,
                              void* d_out, int out_size, void* d_ws, size_t ws_size,
                              hipStream_t stream) {
    const float* z       = (const float*)d_in[0];
    const float* t       = (const float*)d_in[1];
    const float* e       = (const float*)d_in[2];
    const float* log_tau = (const float*)d_in[3];
    const float* E       = (const float*)d_in[4];
    const float* L       = (const float*)d_in[5];
    float* out = (float*)d_out;

    const int B = in_sizes[1];   // 8192
    const int m = in_sizes[5];   // 256

    char* w = (char*)d_ws;
    __hip_bfloat16* hz = (__hip_bfloat16*)w;                 // B*m bf16
    __hip_bfloat16* hy = hz + (size_t)B * m;                 // B*m bf16
    float* ST  = (float*)(hy + (size_t)B * m);               // m*m f32
    float* g   = ST + (size_t)m * m;                         // B f32
    float* acc = g + B;                                      // B f32

    suffix_kernel<<<m, 256, 0, stream>>>(E, ST, m);
    prep_kernel<<<B / 4, 256, 0, stream>>>(z, t, e, log_tau, E, L, ST, hz, hy, g, acc, B, m);
    dim3 grid2(B / BN, B / BM);
    gemm_lse_kernel<<<grid2, 512, 0, stream>>>(hz, hy, acc, B, m);
    finalize_kernel<<<(B + 255) / 256, 256, 0, stream>>>(acc, g, out, B);
}